// Round 14
// baseline (673.113 us; speedup 1.0000x reference)
//
#include <hip/hip_runtime.h>
#include <hip/hip_bf16.h>

#define T_TOK 1024
#define H_DIM 1024
#define I_DIM 1408
#define NE 16
#define NEP 18   // 16 routed + 2 pseudo (shared expert = two I=1408 halves)
#define BM 256   // token tile per block

typedef __attribute__((ext_vector_type(8))) __bf16 bf16x8;
typedef __attribute__((ext_vector_type(4))) float f32x4;

__device__ __forceinline__ bf16x8 cvt8(float4 a, float4 b) {
    bf16x8 r;
    r[0] = (__bf16)a.x; r[1] = (__bf16)a.y; r[2] = (__bf16)a.z; r[3] = (__bf16)a.w;
    r[4] = (__bf16)b.x; r[5] = (__bf16)b.y; r[6] = (__bf16)b.z; r[7] = (__bf16)b.w;
    return r;
}

// async global->LDS DMA, 16B per lane; LDS dest = wave-uniform base + lane*16
__device__ __forceinline__ void gll16(const float* g, float* l) {
    __builtin_amdgcn_global_load_lds(
        (const __attribute__((address_space(1))) void*)g,
        (__attribute__((address_space(3))) void*)l, 16, 0, 0);
}

// ---------------------------------------------------------------- gate ------
__global__ __launch_bounds__(256) void gate_kernel(
    const float* __restrict__ x, const float* __restrict__ gw,
    const float* __restrict__ gb,
    int* __restrict__ counts, int* __restrict__ etok, float* __restrict__ ew)
{
    const int t = blockIdx.x;
    const int tid = threadIdx.x;
    const int lane = tid & 63, w = tid >> 6;
    __shared__ float red[4][NE];

    float s[NE];
#pragma unroll
    for (int e = 0; e < NE; ++e) s[e] = 0.f;
    const float* xr = x + (size_t)t * H_DIM;
#pragma unroll
    for (int j = 0; j < 4; ++j) {
        int i = tid + j * 256;
        float xv = xr[i];
#pragma unroll
        for (int e = 0; e < NE; ++e) s[e] += xv * gw[e * H_DIM + i];
    }
#pragma unroll
    for (int e = 0; e < NE; ++e) {
        for (int off = 32; off > 0; off >>= 1) s[e] += __shfl_xor(s[e], off);
    }
    if (lane == 0) {
#pragma unroll
        for (int e = 0; e < NE; ++e) red[w][e] = s[e];
    }
    __syncthreads();
    if (tid == 0) {
        float scores[NE], sfc[NE];
#pragma unroll
        for (int e = 0; e < NE; ++e) {
            float lg = red[0][e] + red[1][e] + red[2][e] + red[3][e];
            scores[e] = 1.f / (1.f + __expf(-lg));
            sfc[e] = scores[e] + gb[e];
        }
        float gsc[4];
#pragma unroll
        for (int g = 0; g < 4; ++g) {
            float m1 = -1e30f, m2 = -1e30f;
#pragma unroll
            for (int j = 0; j < 4; ++j) {
                float v = sfc[4 * g + j];
                if (v > m1) { m2 = m1; m1 = v; } else if (v > m2) { m2 = v; }
            }
            gsc[g] = m1 + m2;
        }
        int g1 = 0;
        for (int g = 1; g < 4; ++g) if (gsc[g] > gsc[g1]) g1 = g;
        int g2 = -1;
        for (int g = 0; g < 4; ++g) {
            if (g == g1) continue;
            if (g2 < 0 || gsc[g] > gsc[g2]) g2 = g;
        }
        float tmp[NE];
#pragma unroll
        for (int e = 0; e < NE; ++e) {
            int gg = e >> 2;
            tmp[e] = (gg == g1 || gg == g2) ? sfc[e] : 0.0f;
        }
        int idxs[4]; float wk[4]; float wsum = 0.f;
#pragma unroll
        for (int k = 0; k < 4; ++k) {
            int bi = 0;
            for (int e = 1; e < NE; ++e) if (tmp[e] > tmp[bi]) bi = e;
            idxs[k] = bi; wk[k] = scores[bi]; wsum += scores[bi];
            tmp[bi] = -1e30f;
        }
        float inv = 1.f / (wsum + 1e-20f);
        for (int k = 0; k < 4; ++k) {
            int e = idxs[k];
            int pos = atomicAdd(&counts[e], 1);
            etok[e * T_TOK + pos] = t;
            ew[e * T_TOK + pos] = wk[k] * inv;   // SCALE = 1.0
        }
    }
}

// ---------------------------------------------------- x f32 -> bf16 ---------
__global__ __launch_bounds__(256) void cvtx_kernel(
    const float* __restrict__ x, __hip_bfloat16* __restrict__ x_bf)
{
    int i = (blockIdx.x * 256 + threadIdx.x) * 4;
    float4 v = ((const float4*)x)[i >> 2];
    x_bf[i + 0] = __float2bfloat16(v.x);
    x_bf[i + 1] = __float2bfloat16(v.y);
    x_bf[i + 2] = __float2bfloat16(v.z);
    x_bf[i + 3] = __float2bfloat16(v.w);
}

// ------------------------------------------------------------- gate/up ------
// Grid (22, ne, 4). Block = 256 thr = 4 waves x 64 tokens (BM=256 revert).
// RING-4, DEPTH-3 prefetch: step k issues pair{A(k+3), DMA(k+3)}; wait
// vmcnt(16) drains exactly pair k (8 ops) and leaves TWO pairs (16 ops) in
// flight ACROSS the barrier. Depth-1 (rounds 4/7/12) paid full effective
// memory latency (~4k cy) per barrier-locked step -> 10k cy/step observed;
// depth-3 covers it, targeting the ~3.2k cy bandwidth-fair share.
// K-loop unrolled x4 so buffer/A-register indices are compile-time.
__global__ __launch_bounds__(256, 2) void gateup_kernel(
    const __hip_bfloat16* __restrict__ x_bf,
    const float* __restrict__ gproj, const float* __restrict__ uproj,
    const float* __restrict__ sgw, const float* __restrict__ suw,
    const int* __restrict__ counts, const int* __restrict__ etok,
    __hip_bfloat16* __restrict__ act, int e0)
{
    const int slot = blockIdx.y;
    const int e = e0 + slot;
    const int cnt = (e < NE) ? counts[e] : T_TOK;
    const int row0 = blockIdx.z * BM;
    if (row0 >= cnt) return;

    __shared__ int toks[BM];
    __shared__ __align__(16) float Bg[4][2048];   // [buf][64 rows x 32 K f32]
    __shared__ __align__(16) float Bu[4][2048];

    const int tid = threadIdx.x;
    {
        int r = row0 + tid;
        toks[tid] = (e < NE) ? ((r < cnt) ? etok[e * T_TOK + r] : 0) : r;
    }

    const int nb0 = blockIdx.x * 64;
    const float *wg, *wu;
    if (e < NE) {
        wg = gproj + (size_t)e * I_DIM * H_DIM;
        wu = uproj + (size_t)e * I_DIM * H_DIM;
    } else {
        wg = sgw + (size_t)(e - NE) * I_DIM * H_DIM;
        wu = suw + (size_t)(e - NE) * I_DIM * H_DIM;
    }

    const int lane = tid & 63;
    const int w = tid >> 6;           // 0..3
    const int col = lane & 15, kq = lane >> 4;

    // producer: wave w stages chunks {2w,2w+1} (1KB each) per matrix.
    // chunk c: lane l -> row c*8+(l>>3), slot l&7; source slot s^(row&7).
    const int lr8 = lane >> 3;
    const int sgx = (lane & 7) ^ lr8;
    const float* pgW[2]; const float* puW[2];
#pragma unroll
    for (int j = 0; j < 2; ++j) {
        int c = 2 * w + j;
        pgW[j] = wg + (size_t)(nb0 + c * 8 + lr8) * H_DIM + sgx * 4;
        puW[j] = wu + (size_t)(nb0 + c * 8 + lr8) * H_DIM + sgx * 4;
    }
    const int ldsw0 = (2 * w) * 256, ldsw1 = (2 * w + 1) * 256;

    // consumer: fragment ni, half h: row=ni*16+col,
    // f32 idx = row*32 + ((kq*2+h)^(row&7))*4
    int offs[4][2];
#pragma unroll
    for (int ni = 0; ni < 4; ++ni) {
        int row = ni * 16 + col;
#pragma unroll
        for (int h = 0; h < 2; ++h)
            offs[ni][h] = row * 32 + (((kq * 2 + h) ^ (row & 7)) << 2);
    }

    __syncthreads();   // toks visible

    const __hip_bfloat16* ar[4];
#pragma unroll
    for (int mi = 0; mi < 4; ++mi)
        ar[mi] = x_bf + (size_t)toks[w * 64 + mi * 16 + col] * H_DIM + kq * 8;

    f32x4 accg[4][4], accu[4][4];
#pragma unroll
    for (int mi = 0; mi < 4; ++mi)
#pragma unroll
        for (int ni = 0; ni < 4; ++ni) {
            accg[mi][ni] = (f32x4){0.f, 0.f, 0.f, 0.f};
            accu[mi][ni] = (f32x4){0.f, 0.f, 0.f, 0.f};
        }

    bf16x8 a[4][4];   // [phase k&3][mi] — compile-time indexed after unroll

    // prologue: pairs 0,1,2 (order per pair: A x4 then DMA x4)
#pragma unroll
    for (int p = 0; p < 3; ++p) {
#pragma unroll
        for (int mi = 0; mi < 4; ++mi)
            a[p][mi] = *(const bf16x8*)(ar[mi] + p * 32);
        gll16(pgW[0] + p * 32, &Bg[p][ldsw0]);
        gll16(pgW[1] + p * 32, &Bg[p][ldsw1]);
        gll16(puW[0] + p * 32, &Bu[p][ldsw0]);
        gll16(puW[1] + p * 32, &Bu[p][ldsw1]);
    }

#define GU_COMPUTE(KK)                                                         \
    {                                                                          \
        const float* bgR = &Bg[(KK)][0];                                       \
        const float* buR = &Bu[(KK)][0];                                       \
        bf16x8 bg[4], bu[4];                                                   \
        _Pragma("unroll")                                                      \
        for (int ni = 0; ni < 4; ++ni) {                                       \
            float4 lo = *(const float4*)(bgR + offs[ni][0]);                   \
            float4 hi = *(const float4*)(bgR + offs[ni][1]);                   \
            bg[ni] = cvt8(lo, hi);                                             \
            float4 lo2 = *(const float4*)(buR + offs[ni][0]);                  \
            float4 hi2 = *(const float4*)(buR + offs[ni][1]);                  \
            bu[ni] = cvt8(lo2, hi2);                                           \
        }                                                                      \
        _Pragma("unroll")                                                      \
        for (int mi = 0; mi < 4; ++mi)                                         \
            _Pragma("unroll")                                                  \
            for (int ni = 0; ni < 4; ++ni) {                                   \
                accg[mi][ni] = __builtin_amdgcn_mfma_f32_16x16x32_bf16(        \
                    a[(KK)][mi], bg[ni], accg[mi][ni], 0, 0, 0);               \
                accu[mi][ni] = __builtin_amdgcn_mfma_f32_16x16x32_bf16(        \
                    a[(KK)][mi], bu[ni], accu[mi][ni], 0, 0, 0);               \
            }                                                                  \
    }

    for (int kt = 0; kt < 7; ++kt) {          // k = 0..27
#pragma unroll
        for (int kk = 0; kk < 4; ++kk) {
            const int k = kt * 4 + kk;
            asm volatile("s_waitcnt vmcnt(16)" ::: "memory");
            __builtin_amdgcn_s_barrier();
            __builtin_amdgcn_sched_barrier(0);
            {   // issue pair k+3 into buf (kk+3)&3
                const int kp = k + 3, bp = (kk + 3) & 3;
#pragma unroll
                for (int mi = 0; mi < 4; ++mi)
                    a[bp][mi] = *(const bf16x8*)(ar[mi] + kp * 32);
                const int ko = kp * 32;
                gll16(pgW[0] + ko, &Bg[bp][ldsw0]);
                gll16(pgW[1] + ko, &Bg[bp][ldsw1]);
                gll16(puW[0] + ko, &Bu[bp][ldsw0]);
                gll16(puW[1] + ko, &Bu[bp][ldsw1]);
            }
            __builtin_amdgcn_sched_barrier(0);
            GU_COMPUTE(kk);
        }
    }
    // epilogue k = 28..31 (buf = k&3 = kk); outstanding pairs shrink
#pragma unroll
    for (int kk = 0; kk < 4; ++kk) {
        if (kk == 0)      asm volatile("s_waitcnt vmcnt(16)" ::: "memory");
        else if (kk == 1) asm volatile("s_waitcnt vmcnt(16)" ::: "memory");
        else if (kk == 2) asm volatile("s_waitcnt vmcnt(8)" ::: "memory");
        else              asm volatile("s_waitcnt vmcnt(0)" ::: "memory");
        __builtin_amdgcn_s_barrier();
        __builtin_amdgcn_sched_barrier(0);
        if (kk == 0) {   // issue last pair (k=31) into buf 3
#pragma unroll
            for (int mi = 0; mi < 4; ++mi)
                a[3][mi] = *(const bf16x8*)(ar[mi] + 31 * 32);
            gll16(pgW[0] + 31 * 32, &Bg[3][ldsw0]);
            gll16(pgW[1] + 31 * 32, &Bg[3][ldsw1]);
            gll16(puW[0] + 31 * 32, &Bu[3][ldsw0]);
            gll16(puW[1] + 31 * 32, &Bu[3][ldsw1]);
        }
        __builtin_amdgcn_sched_barrier(0);
        GU_COMPUTE(kk);
    }
#undef GU_COMPUTE

    // epilogue: silu(g)*u -> act (zeros for padded rows so down reads zeros)
#pragma unroll
    for (int mi = 0; mi < 4; ++mi)
#pragma unroll
        for (int ni = 0; ni < 4; ++ni)
#pragma unroll
            for (int r = 0; r < 4; ++r) {
                int lrow = w * 64 + mi * 16 + kq * 4 + r;
                int grow = row0 + lrow;
                float g = accg[mi][ni][r];
                float a2 = (grow < cnt) ? (g / (1.f + __expf(-g)) * accu[mi][ni][r]) : 0.f;
                act[((size_t)slot * T_TOK + grow) * I_DIM + nb0 + ni * 16 + col] =
                    __float2bfloat16(a2);
            }
}

// ---------------------------------------------------------------- down ------
// 1-D grid, XCD-clustered (hw%8 picks the group). BM=256, 256 thr. Same
// ring-4 depth-3 discipline; pair = A(4) + DMA(2) = 6 ops -> steady
// vmcnt(12), tail 12/12/6/0. K = I_DIM/32 = 44 = 10*4 + 4.
__global__ __launch_bounds__(256, 3) void down_kernel(
    const __hip_bfloat16* __restrict__ act,
    const float* __restrict__ dproj, const float* __restrict__ sdw,
    const int* __restrict__ counts, const int* __restrict__ etok,
    const float* __restrict__ ew, float* __restrict__ y, int e0, int ne)
{
    const int hw = blockIdx.x;
    const int c8 = hw & 7, t = hw >> 3;
    const int nbt = t & 15, gh = t >> 4;
    const int g = c8 + 8 * gh;
    if (g >= ne * 4) return;           // Gp padding
    const int slot = g % ne;
    const int z = g / ne;

    const int e = e0 + slot;
    const int cnt = (e < NE) ? counts[e] : T_TOK;
    const int row0 = z * BM;
    if (row0 >= cnt) return;

    __shared__ int toks[BM];
    __shared__ float wts[BM];
    __shared__ __align__(16) float Bd[4][2048];

    const int tid = threadIdx.x;
    {
        int r = row0 + tid;
        if (e < NE) {
            bool ok = r < cnt;
            toks[tid] = ok ? etok[e * T_TOK + r] : 0;
            wts[tid]  = ok ? ew[e * T_TOK + r] : 0.f;
        } else { toks[tid] = r; wts[tid] = 1.f; }
    }

    const int nb0 = nbt * 64;
    const float* wd;
    int wstride;
    if (e < NE) { wd = dproj + (size_t)e * H_DIM * I_DIM; wstride = I_DIM; }
    else        { wd = sdw + (size_t)(e - NE) * I_DIM;    wstride = 2 * I_DIM; }

    const int lane = tid & 63;
    const int w = tid >> 6;
    const int col = lane & 15, kq = lane >> 4;

    const int lr8 = lane >> 3;
    const int sgx = (lane & 7) ^ lr8;
    const float* pdW[2];
#pragma unroll
    for (int j = 0; j < 2; ++j) {
        int c = 2 * w + j;
        pdW[j] = wd + (size_t)(nb0 + c * 8 + lr8) * wstride + sgx * 4;
    }
    const int ldsw0 = (2 * w) * 256, ldsw1 = (2 * w + 1) * 256;

    int offs[4][2];
#pragma unroll
    for (int ni = 0; ni < 4; ++ni) {
        int row = ni * 16 + col;
#pragma unroll
        for (int h = 0; h < 2; ++h)
            offs[ni][h] = row * 32 + (((kq * 2 + h) ^ (row & 7)) << 2);
    }

    __syncthreads();   // toks/wts visible

    const __hip_bfloat16* ar[4];
#pragma unroll
    for (int mi = 0; mi < 4; ++mi)
        ar[mi] = act + ((size_t)slot * T_TOK + row0 + w * 64 + mi * 16 + col) * I_DIM + kq * 8;

    f32x4 acc[4][4];
#pragma unroll
    for (int mi = 0; mi < 4; ++mi)
#pragma unroll
        for (int ni = 0; ni < 4; ++ni) acc[mi][ni] = (f32x4){0.f, 0.f, 0.f, 0.f};

    bf16x8 a[4][4];
    // prologue: pairs 0,1,2
#pragma unroll
    for (int p = 0; p < 3; ++p) {
#pragma unroll
        for (int mi = 0; mi < 4; ++mi)
            a[p][mi] = *(const bf16x8*)(ar[mi] + p * 32);
        gll16(pdW[0] + p * 32, &Bd[p][ldsw0]);
        gll16(pdW[1] + p * 32, &Bd[p][ldsw1]);
    }

#define D_COMPUTE(KK)                                                          \
    {                                                                          \
        const float* bdR = &Bd[(KK)][0];                                       \
        bf16x8 b[4];                                                           \
        _Pragma("unroll")                                                      \
        for (int ni = 0; ni < 4; ++ni) {                                       \
            float4 lo = *(const float4*)(bdR + offs[ni][0]);                   \
            float4 hi = *(const float4*)(bdR + offs[ni][1]);                   \
            b[ni] = cvt8(lo, hi);                                              \
        }                                                                      \
        _Pragma("unroll")                                                      \
        for (int mi = 0; mi < 4; ++mi)                                         \
            _Pragma("unroll")                                                  \
            for (int ni = 0; ni < 4; ++ni)                                     \
                acc[mi][ni] = __builtin_amdgcn_mfma_f32_16x16x32_bf16(         \
                    a[(KK)][mi], b[ni], acc[mi][ni], 0, 0, 0);                 \
    }

    const int KS = I_DIM / 32;   // 44
    for (int kt = 0; kt < 10; ++kt) {        // k = 0..39
#pragma unroll
        for (int kk = 0; kk < 4; ++kk) {
            const int k = kt * 4 + kk;
            asm volatile("s_waitcnt vmcnt(12)" ::: "memory");
            __builtin_amdgcn_s_barrier();
            __builtin_amdgcn_sched_barrier(0);
            {
                const int kp = k + 3, bp = (kk + 3) & 3;
#pragma unroll
                for (int mi = 0; mi < 4; ++mi)
                    a[bp][mi] = *(const bf16x8*)(ar[mi] + kp * 32);
                gll16(pdW[0] + kp * 32, &Bd[bp][ldsw0]);
                gll16(pdW[1] + kp * 32, &Bd[bp][ldsw1]);
            }
            __builtin_amdgcn_sched_barrier(0);
            D_COMPUTE(kk);
        }
    }
    // epilogue k = 40..43 (buf = k&3 = kk)
#pragma unroll
    for (int kk = 0; kk < 4; ++kk) {
        if (kk == 0)      asm volatile("s_waitcnt vmcnt(12)" ::: "memory");
        else if (kk == 1) asm volatile("s_waitcnt vmcnt(12)" ::: "memory");
        else if (kk == 2) asm volatile("s_waitcnt vmcnt(6)" ::: "memory");
        else              asm volatile("s_waitcnt vmcnt(0)" ::: "memory");
        __builtin_amdgcn_s_barrier();
        __builtin_amdgcn_sched_barrier(0);
        if (kk == 0) {   // issue last pair (k=43) into buf 3
#pragma unroll
            for (int mi = 0; mi < 4; ++mi)
                a[3][mi] = *(const bf16x8*)(ar[mi] + 43 * 32);
            gll16(pdW[0] + 43 * 32, &Bd[3][ldsw0]);
            gll16(pdW[1] + 43 * 32, &Bd[3][ldsw1]);
        }
        __builtin_amdgcn_sched_barrier(0);
        D_COMPUTE(kk);
    }
#undef D_COMPUTE
    (void)KS;

#pragma unroll
    for (int mi = 0; mi < 4; ++mi)
#pragma unroll
        for (int ni = 0; ni < 4; ++ni)
#pragma unroll
            for (int r = 0; r < 4; ++r) {
                int lrow = w * 64 + mi * 16 + kq * 4 + r;
                int grow = row0 + lrow;
                if (grow < cnt)
                    atomicAdd(&y[(size_t)toks[lrow] * H_DIM + nb0 + ni * 16 + col],
                              acc[mi][ni][r] * wts[lrow]);
            }
}

// -------------------------------------------------------------- launch ------
extern "C" void kernel_launch(void* const* d_in, const int* in_sizes, int n_in,
                              void* d_out, int out_size, void* d_ws, size_t ws_size,
                              hipStream_t stream) {
    (void)in_sizes; (void)n_in; (void)out_size;
    const float* x  = (const float*)d_in[0];
    const float* gw = (const float*)d_in[1];
    const float* gb = (const float*)d_in[2];
    const float* gp = (const float*)d_in[3];
    const float* up = (const float*)d_in[4];
    const float* dp = (const float*)d_in[5];
    const float* sg = (const float*)d_in[6];
    const float* su = (const float*)d_in[7];
    const float* sd = (const float*)d_in[8];
    float* out = (float*)d_out;

    char* ws = (char*)d_ws;
    int*   counts = (int*)ws;                                    // @0      (64 B)
    int*   etok   = (int*)(ws + 256);                            // 64 KB
    float* ew     = (float*)(ws + 256 + 65536);                  // 64 KB
    __hip_bfloat16* x_bf = (__hip_bfloat16*)(ws + 131328);       // 2 MB
    __hip_bfloat16* act  = (__hip_bfloat16*)(ws + 2228480);      // up to ~52 MB

    size_t fixed = 2228480;
    size_t per_e = (size_t)T_TOK * I_DIM * 2;                    // 2.75 MB / slot
    int cap = NEP;
    if (ws_size < fixed + (size_t)NEP * per_e) {
        cap = (ws_size > fixed + per_e) ? (int)((ws_size - fixed) / per_e) : 1;
        if (cap < 1) cap = 1;
    }

    hipMemsetAsync(ws, 0, 256, stream);                          // counts
    hipMemsetAsync(out, 0, (size_t)T_TOK * H_DIM * 4, stream);   // d_out is poisoned

    gate_kernel<<<dim3(T_TOK), dim3(256), 0, stream>>>(x, gw, gb, counts, etok, ew);
    cvtx_kernel<<<dim3(1024), dim3(256), 0, stream>>>(x, x_bf);

    for (int e0 = 0; e0 < NEP; e0 += cap) {
        int ne = NEP - e0 < cap ? NEP - e0 : cap;
        gateup_kernel<<<dim3(I_DIM / 64, ne, T_TOK / BM), dim3(256), 0, stream>>>(
            x_bf, gp, up, sg, su, counts, etok, act, e0);
        int Gp = ((ne * 4 + 7) / 8) * 8;                         // XCD-bijective pad
        down_kernel<<<dim3(16 * Gp), dim3(256), 0, stream>>>(
            act, dp, sd, counts, etok, ew, out, e0, ne);
    }
}

// Round 15
// 554.072 us; speedup vs baseline: 1.2148x; 1.2148x over previous
//
#include <hip/hip_runtime.h>
#include <hip/hip_bf16.h>

#define T_TOK 1024
#define H_DIM 1024
#define I_DIM 1408
#define NE 16
#define NEP 18   // 16 routed + 2 pseudo (shared expert = two I=1408 halves)
#define BM 256   // token tile per block

typedef __attribute__((ext_vector_type(8))) __bf16 bf16x8;
typedef __attribute__((ext_vector_type(4))) float f32x4;

__device__ __forceinline__ bf16x8 cvt8(float4 a, float4 b) {
    bf16x8 r;
    r[0] = (__bf16)a.x; r[1] = (__bf16)a.y; r[2] = (__bf16)a.z; r[3] = (__bf16)a.w;
    r[4] = (__bf16)b.x; r[5] = (__bf16)b.y; r[6] = (__bf16)b.z; r[7] = (__bf16)b.w;
    return r;
}

// async global->LDS DMA, 16B per lane; LDS dest = wave-uniform base + lane*16
__device__ __forceinline__ void gll16(const float* g, float* l) {
    __builtin_amdgcn_global_load_lds(
        (const __attribute__((address_space(1))) void*)g,
        (__attribute__((address_space(3))) void*)l, 16, 0, 0);
}

// ---------------------------------------------------------------- gate ------
__global__ __launch_bounds__(256) void gate_kernel(
    const float* __restrict__ x, const float* __restrict__ gw,
    const float* __restrict__ gb,
    int* __restrict__ counts, int* __restrict__ etok, float* __restrict__ ew)
{
    const int t = blockIdx.x;
    const int tid = threadIdx.x;
    const int lane = tid & 63, w = tid >> 6;
    __shared__ float red[4][NE];

    float s[NE];
#pragma unroll
    for (int e = 0; e < NE; ++e) s[e] = 0.f;
    const float* xr = x + (size_t)t * H_DIM;
#pragma unroll
    for (int j = 0; j < 4; ++j) {
        int i = tid + j * 256;
        float xv = xr[i];
#pragma unroll
        for (int e = 0; e < NE; ++e) s[e] += xv * gw[e * H_DIM + i];
    }
#pragma unroll
    for (int e = 0; e < NE; ++e) {
        for (int off = 32; off > 0; off >>= 1) s[e] += __shfl_xor(s[e], off);
    }
    if (lane == 0) {
#pragma unroll
        for (int e = 0; e < NE; ++e) red[w][e] = s[e];
    }
    __syncthreads();
    if (tid == 0) {
        float scores[NE], sfc[NE];
#pragma unroll
        for (int e = 0; e < NE; ++e) {
            float lg = red[0][e] + red[1][e] + red[2][e] + red[3][e];
            scores[e] = 1.f / (1.f + __expf(-lg));
            sfc[e] = scores[e] + gb[e];
        }
        float gsc[4];
#pragma unroll
        for (int g = 0; g < 4; ++g) {
            float m1 = -1e30f, m2 = -1e30f;
#pragma unroll
            for (int j = 0; j < 4; ++j) {
                float v = sfc[4 * g + j];
                if (v > m1) { m2 = m1; m1 = v; } else if (v > m2) { m2 = v; }
            }
            gsc[g] = m1 + m2;
        }
        int g1 = 0;
        for (int g = 1; g < 4; ++g) if (gsc[g] > gsc[g1]) g1 = g;
        int g2 = -1;
        for (int g = 0; g < 4; ++g) {
            if (g == g1) continue;
            if (g2 < 0 || gsc[g] > gsc[g2]) g2 = g;
        }
        float tmp[NE];
#pragma unroll
        for (int e = 0; e < NE; ++e) {
            int gg = e >> 2;
            tmp[e] = (gg == g1 || gg == g2) ? sfc[e] : 0.0f;
        }
        int idxs[4]; float wk[4]; float wsum = 0.f;
#pragma unroll
        for (int k = 0; k < 4; ++k) {
            int bi = 0;
            for (int e = 1; e < NE; ++e) if (tmp[e] > tmp[bi]) bi = e;
            idxs[k] = bi; wk[k] = scores[bi]; wsum += scores[bi];
            tmp[bi] = -1e30f;
        }
        float inv = 1.f / (wsum + 1e-20f);
        for (int k = 0; k < 4; ++k) {
            int e = idxs[k];
            int pos = atomicAdd(&counts[e], 1);
            etok[e * T_TOK + pos] = t;
            ew[e * T_TOK + pos] = wk[k] * inv;   // SCALE = 1.0
        }
    }
}

// ---------------------------------------------------- x f32 -> bf16 ---------
__global__ __launch_bounds__(256) void cvtx_kernel(
    const float* __restrict__ x, __hip_bfloat16* __restrict__ x_bf)
{
    int i = (blockIdx.x * 256 + threadIdx.x) * 4;
    float4 v = ((const float4*)x)[i >> 2];
    x_bf[i + 0] = __float2bfloat16(v.x);
    x_bf[i + 1] = __float2bfloat16(v.y);
    x_bf[i + 2] = __float2bfloat16(v.z);
    x_bf[i + 3] = __float2bfloat16(v.w);
}

// ------------------------------------------------------------- gate/up ------
// Grid (44, ne, 4). Block = 256 thr = 4 waves x 64 tokens; NB=32 I-cols.
// OCCUPANCY FIX: NB 64->32 halves the dual accumulator (128->64 AGPR) so
// regs/wave ~ 90 VGPR + 64 AGPR -> 3 waves/SIMD (launch_bounds(256,3)) and
// doubles active blocks to ~4/CU (44x24=1056). Rounds 4/7/12 all pinned at
// ~134us regardless of schedule because 252 regs/wave capped 2 waves/SIMD
// and half the CUs ran a single barrier-locked block (Occupancy 17%).
// B-traffic unchanged (half-width tile read once each). Ring-3 + counted
// vmcnt kept: per step issue A(k+1):4, D(k+2):2; steady queue at wait =
// [D(k):2, A(k):4, D(k+1):2] -> vmcnt(2) drains D(k)+A(k), leaves D(k+1).
__global__ __launch_bounds__(256, 3) void gateup_kernel(
    const __hip_bfloat16* __restrict__ x_bf,
    const float* __restrict__ gproj, const float* __restrict__ uproj,
    const float* __restrict__ sgw, const float* __restrict__ suw,
    const int* __restrict__ counts, const int* __restrict__ etok,
    __hip_bfloat16* __restrict__ act, int e0)
{
    const int slot = blockIdx.y;
    const int e = e0 + slot;
    const int cnt = (e < NE) ? counts[e] : T_TOK;
    const int row0 = blockIdx.z * BM;
    if (row0 >= cnt) return;

    __shared__ int toks[BM];
    __shared__ __align__(16) float Bg[3][1024];   // [buf][32 rows x 32 K f32]
    __shared__ __align__(16) float Bu[3][1024];

    const int tid = threadIdx.x;
    {
        int r = row0 + tid;
        toks[tid] = (e < NE) ? ((r < cnt) ? etok[e * T_TOK + r] : 0) : r;
    }

    const int nb0 = blockIdx.x * 32;
    const float *wg, *wu;
    if (e < NE) {
        wg = gproj + (size_t)e * I_DIM * H_DIM;
        wu = uproj + (size_t)e * I_DIM * H_DIM;
    } else {
        wg = sgw + (size_t)(e - NE) * I_DIM * H_DIM;
        wu = suw + (size_t)(e - NE) * I_DIM * H_DIM;
    }

    const int lane = tid & 63;
    const int w = tid >> 6;           // 0..3
    const int col = lane & 15, kq = lane >> 4;

    // producer: wave w stages rows w*8..w*8+7 of each matrix (1KB each).
    // lane l -> row w*8+(l>>3), slot l&7; source slot pre-swizzled s^(row&7).
    const int lr8 = lane >> 3;
    const int sgx = (lane & 7) ^ lr8;
    const float* pgW = wg + (size_t)(nb0 + w * 8 + lr8) * H_DIM + sgx * 4;
    const float* puW = wu + (size_t)(nb0 + w * 8 + lr8) * H_DIM + sgx * 4;
    const int ldsw = w * 256;   // f32 index

    // consumer: fragment ni (0..1), half h: row=ni*16+col,
    // f32 idx = row*32 + ((kq*2+h)^(row&7))*4
    int offs[2][2];
#pragma unroll
    for (int ni = 0; ni < 2; ++ni) {
        int row = ni * 16 + col;
#pragma unroll
        for (int h = 0; h < 2; ++h)
            offs[ni][h] = row * 32 + (((kq * 2 + h) ^ (row & 7)) << 2);
    }

    __syncthreads();   // toks visible

    const __hip_bfloat16* ar[4];
#pragma unroll
    for (int mi = 0; mi < 4; ++mi)
        ar[mi] = x_bf + (size_t)toks[w * 64 + mi * 16 + col] * H_DIM + kq * 8;

    f32x4 accg[4][2], accu[4][2];
#pragma unroll
    for (int mi = 0; mi < 4; ++mi)
#pragma unroll
        for (int ni = 0; ni < 2; ++ni) {
            accg[mi][ni] = (f32x4){0.f, 0.f, 0.f, 0.f};
            accu[mi][ni] = (f32x4){0.f, 0.f, 0.f, 0.f};
        }

    // prologue: A(0), then DMA k=0 -> buf0, k=1 -> buf1 (queue: A0,D0,D1)
    bf16x8 a_cur[4], a_nxt[4];
#pragma unroll
    for (int mi = 0; mi < 4; ++mi) a_cur[mi] = *(const bf16x8*)ar[mi];
    gll16(pgW, &Bg[0][ldsw]); gll16(puW, &Bu[0][ldsw]);
    gll16(pgW + 32, &Bg[1][ldsw]); gll16(puW + 32, &Bu[1][ldsw]);

    int br = 0;   // ring buffer holding step k
    for (int k = 0; k < 32; ++k) {
        // drain D(k)+A(k) (6 oldest), leave D(k+1) (2) in flight
        asm volatile("s_waitcnt vmcnt(2)" ::: "memory");
        __builtin_amdgcn_s_barrier();
        __builtin_amdgcn_sched_barrier(0);
        if (k + 1 < 32) {   // prefetch A(k+1)
#pragma unroll
            for (int mi = 0; mi < 4; ++mi)
                a_nxt[mi] = *(const bf16x8*)(ar[mi] + (k + 1) * 32);
        }
        __builtin_amdgcn_sched_barrier(0);
        if (k + 2 < 32) {   // stage k+2 into buf (k+2)%3 (== (k-1)%3)
            int b2 = br + 2; if (b2 >= 3) b2 -= 3;
            const int ko = (k + 2) * 32;
            gll16(pgW + ko, &Bg[0][0] + b2 * 1024 + ldsw);
            gll16(puW + ko, &Bu[0][0] + b2 * 1024 + ldsw);
        }
        __builtin_amdgcn_sched_barrier(0);
        const float* bgR = &Bg[0][0] + br * 1024;
        const float* buR = &Bu[0][0] + br * 1024;
        bf16x8 bg[2], bu[2];
#pragma unroll
        for (int ni = 0; ni < 2; ++ni) {
            float4 lo = *(const float4*)(bgR + offs[ni][0]);
            float4 hi = *(const float4*)(bgR + offs[ni][1]);
            bg[ni] = cvt8(lo, hi);
            float4 lo2 = *(const float4*)(buR + offs[ni][0]);
            float4 hi2 = *(const float4*)(buR + offs[ni][1]);
            bu[ni] = cvt8(lo2, hi2);
        }
#pragma unroll
        for (int mi = 0; mi < 4; ++mi)
#pragma unroll
            for (int ni = 0; ni < 2; ++ni) {
                accg[mi][ni] = __builtin_amdgcn_mfma_f32_16x16x32_bf16(a_cur[mi], bg[ni], accg[mi][ni], 0, 0, 0);
                accu[mi][ni] = __builtin_amdgcn_mfma_f32_16x16x32_bf16(a_cur[mi], bu[ni], accu[mi][ni], 0, 0, 0);
            }
#pragma unroll
        for (int mi = 0; mi < 4; ++mi) a_cur[mi] = a_nxt[mi];
        br += 1; if (br >= 3) br = 0;
    }

    // epilogue: silu(g)*u -> act (zeros for padded rows so down reads zeros)
#pragma unroll
    for (int mi = 0; mi < 4; ++mi)
#pragma unroll
        for (int ni = 0; ni < 2; ++ni)
#pragma unroll
            for (int r = 0; r < 4; ++r) {
                int lrow = w * 64 + mi * 16 + kq * 4 + r;
                int grow = row0 + lrow;
                float g = accg[mi][ni][r];
                float a = (grow < cnt) ? (g / (1.f + __expf(-g)) * accu[mi][ni][r]) : 0.f;
                act[((size_t)slot * T_TOK + grow) * I_DIM + nb0 + ni * 16 + col] =
                    __float2bfloat16(a);
            }
}

// ---------------------------------------------------------------- down ------
// 1-D grid, XCD-clustered (hw%8 picks the group -> all 32 nb-blocks of one
// (slot,z) share one XCD's L2 for the act slice). NB=32: acc 32 AGPR,
// ~75 VGPR -> launch_bounds(256,4). Ring-3; per step D batch = 1 gll16 ->
// steady queue [D(k):1, A(k):4, D(k+1):1], wait vmcnt(1).
__global__ __launch_bounds__(256, 4) void down_kernel(
    const __hip_bfloat16* __restrict__ act,
    const float* __restrict__ dproj, const float* __restrict__ sdw,
    const int* __restrict__ counts, const int* __restrict__ etok,
    const float* __restrict__ ew, float* __restrict__ y, int e0, int ne)
{
    const int hw = blockIdx.x;
    const int c8 = hw & 7, t = hw >> 3;
    const int nbt = t & 31, gh = t >> 5;
    const int g = c8 + 8 * gh;
    if (g >= ne * 4) return;           // Gp padding
    const int slot = g % ne;
    const int z = g / ne;

    const int e = e0 + slot;
    const int cnt = (e < NE) ? counts[e] : T_TOK;
    const int row0 = z * BM;
    if (row0 >= cnt) return;

    __shared__ int toks[BM];
    __shared__ float wts[BM];
    __shared__ __align__(16) float Bd[3][1024];

    const int tid = threadIdx.x;
    {
        int r = row0 + tid;
        if (e < NE) {
            bool ok = r < cnt;
            toks[tid] = ok ? etok[e * T_TOK + r] : 0;
            wts[tid]  = ok ? ew[e * T_TOK + r] : 0.f;
        } else { toks[tid] = r; wts[tid] = 1.f; }
    }

    const int nb0 = nbt * 32;
    const float* wd;
    int wstride;
    if (e < NE) { wd = dproj + (size_t)e * H_DIM * I_DIM; wstride = I_DIM; }
    else        { wd = sdw + (size_t)(e - NE) * I_DIM;    wstride = 2 * I_DIM; }

    const int lane = tid & 63;
    const int w = tid >> 6;
    const int col = lane & 15, kq = lane >> 4;

    const int lr8 = lane >> 3;
    const int sgx = (lane & 7) ^ lr8;
    const float* pdW = wd + (size_t)(nb0 + w * 8 + lr8) * wstride + sgx * 4;
    const int ldsw = w * 256;

    int offs[2][2];
#pragma unroll
    for (int ni = 0; ni < 2; ++ni) {
        int row = ni * 16 + col;
#pragma unroll
        for (int h = 0; h < 2; ++h)
            offs[ni][h] = row * 32 + (((kq * 2 + h) ^ (row & 7)) << 2);
    }

    __syncthreads();   // toks/wts visible

    const __hip_bfloat16* ar[4];
#pragma unroll
    for (int mi = 0; mi < 4; ++mi)
        ar[mi] = act + ((size_t)slot * T_TOK + row0 + w * 64 + mi * 16 + col) * I_DIM + kq * 8;

    f32x4 acc[4][2];
#pragma unroll
    for (int mi = 0; mi < 4; ++mi)
#pragma unroll
        for (int ni = 0; ni < 2; ++ni) acc[mi][ni] = (f32x4){0.f, 0.f, 0.f, 0.f};

    const int KS = I_DIM / 32;   // 44
    bf16x8 a_cur[4], a_nxt[4];
#pragma unroll
    for (int mi = 0; mi < 4; ++mi) a_cur[mi] = *(const bf16x8*)ar[mi];
    gll16(pdW, &Bd[0][ldsw]);
    gll16(pdW + 32, &Bd[1][ldsw]);

    int br = 0;
    for (int k = 0; k < KS; ++k) {
        asm volatile("s_waitcnt vmcnt(1)" ::: "memory");
        __builtin_amdgcn_s_barrier();
        __builtin_amdgcn_sched_barrier(0);
        if (k + 1 < KS) {
#pragma unroll
            for (int mi = 0; mi < 4; ++mi)
                a_nxt[mi] = *(const bf16x8*)(ar[mi] + (k + 1) * 32);
        }
        __builtin_amdgcn_sched_barrier(0);
        if (k + 2 < KS) {
            int b2 = br + 2; if (b2 >= 3) b2 -= 3;
            gll16(pdW + (k + 2) * 32, &Bd[0][0] + b2 * 1024 + ldsw);
        }
        __builtin_amdgcn_sched_barrier(0);
        const float* bdR = &Bd[0][0] + br * 1024;
        bf16x8 b[2];
#pragma unroll
        for (int ni = 0; ni < 2; ++ni) {
            float4 lo = *(const float4*)(bdR + offs[ni][0]);
            float4 hi = *(const float4*)(bdR + offs[ni][1]);
            b[ni] = cvt8(lo, hi);
        }
#pragma unroll
        for (int mi = 0; mi < 4; ++mi)
#pragma unroll
            for (int ni = 0; ni < 2; ++ni)
                acc[mi][ni] = __builtin_amdgcn_mfma_f32_16x16x32_bf16(a_cur[mi], b[ni], acc[mi][ni], 0, 0, 0);
#pragma unroll
        for (int mi = 0; mi < 4; ++mi) a_cur[mi] = a_nxt[mi];
        br += 1; if (br >= 3) br = 0;
    }

#pragma unroll
    for (int mi = 0; mi < 4; ++mi)
#pragma unroll
        for (int ni = 0; ni < 2; ++ni)
#pragma unroll
            for (int r = 0; r < 4; ++r) {
                int lrow = w * 64 + mi * 16 + kq * 4 + r;
                int grow = row0 + lrow;
                if (grow < cnt)
                    atomicAdd(&y[(size_t)toks[lrow] * H_DIM + nb0 + ni * 16 + col],
                              acc[mi][ni][r] * wts[lrow]);
            }
}

// -------------------------------------------------------------- launch ------
extern "C" void kernel_launch(void* const* d_in, const int* in_sizes, int n_in,
                              void* d_out, int out_size, void* d_ws, size_t ws_size,
                              hipStream_t stream) {
    (void)in_sizes; (void)n_in; (void)out_size;
    const float* x  = (const float*)d_in[0];
    const float* gw = (const float*)d_in[1];
    const float* gb = (const float*)d_in[2];
    const float* gp = (const float*)d_in[3];
    const float* up = (const float*)d_in[4];
    const float* dp = (const float*)d_in[5];
    const float* sg = (const float*)d_in[6];
    const float* su = (const float*)d_in[7];
    const float* sd = (const float*)d_in[8];
    float* out = (float*)d_out;

    char* ws = (char*)d_ws;
    int*   counts = (int*)ws;                                    // @0      (64 B)
    int*   etok   = (int*)(ws + 256);                            // 64 KB
    float* ew     = (float*)(ws + 256 + 65536);                  // 64 KB
    __hip_bfloat16* x_bf = (__hip_bfloat16*)(ws + 131328);       // 2 MB
    __hip_bfloat16* act  = (__hip_bfloat16*)(ws + 2228480);      // up to ~52 MB

    size_t fixed = 2228480;
    size_t per_e = (size_t)T_TOK * I_DIM * 2;                    // 2.75 MB / slot
    int cap = NEP;
    if (ws_size < fixed + (size_t)NEP * per_e) {
        cap = (ws_size > fixed + per_e) ? (int)((ws_size - fixed) / per_e) : 1;
        if (cap < 1) cap = 1;
    }

    hipMemsetAsync(ws, 0, 256, stream);                          // counts
    hipMemsetAsync(out, 0, (size_t)T_TOK * H_DIM * 4, stream);   // d_out is poisoned

    gate_kernel<<<dim3(T_TOK), dim3(256), 0, stream>>>(x, gw, gb, counts, etok, ew);
    cvtx_kernel<<<dim3(1024), dim3(256), 0, stream>>>(x, x_bf);

    for (int e0 = 0; e0 < NEP; e0 += cap) {
        int ne = NEP - e0 < cap ? NEP - e0 : cap;
        gateup_kernel<<<dim3(I_DIM / 32, ne, T_TOK / BM), dim3(256), 0, stream>>>(
            x_bf, gp, up, sg, su, counts, etok, act, e0);
        int Gp = ((ne * 4 + 7) / 8) * 8;                         // XCD-bijective pad
        down_kernel<<<dim3(32 * Gp), dim3(256), 0, stream>>>(
            act, dp, sd, counts, etok, ew, out, e0, ne);
    }
}

// Round 16
// 492.303 us; speedup vs baseline: 1.3673x; 1.1255x over previous
//
#include <hip/hip_runtime.h>
#include <hip/hip_bf16.h>

#define T_TOK 1024
#define H_DIM 1024
#define I_DIM 1408
#define NE 16
#define NEP 18   // 16 routed + 2 pseudo (shared expert = two I=1408 halves)
#define BM 256   // token tile per block
#define LDB 40   // padded LDS row (32 K bf16 + 8 pad) -> 2-way bank alias only

typedef __attribute__((ext_vector_type(8))) __bf16 bf16x8;
typedef __attribute__((ext_vector_type(4))) float f32x4;

__device__ __forceinline__ bf16x8 cvt8(float4 a, float4 b) {
    bf16x8 r;
    r[0] = (__bf16)a.x; r[1] = (__bf16)a.y; r[2] = (__bf16)a.z; r[3] = (__bf16)a.w;
    r[4] = (__bf16)b.x; r[5] = (__bf16)b.y; r[6] = (__bf16)b.z; r[7] = (__bf16)b.w;
    return r;
}

// ---------------------------------------------------------------- gate ------
// cvtx FUSED: gate already reads every x element once; write x_bf inline
// (removes the separate cvtx dispatch and a second full x read).
__global__ __launch_bounds__(64) void gate_kernel(
    const float* __restrict__ x, const float* __restrict__ gw,
    const float* __restrict__ gb,
    int* __restrict__ counts, int* __restrict__ etok, float* __restrict__ ew,
    __hip_bfloat16* __restrict__ x_bf)
{
    const int t = blockIdx.x;
    const int lane = threadIdx.x;
    float s[NE];
#pragma unroll
    for (int e = 0; e < NE; ++e) s[e] = 0.f;
    const float* xr = x + (size_t)t * H_DIM;
    __hip_bfloat16* xbr = x_bf + (size_t)t * H_DIM;
    for (int i = lane; i < H_DIM; i += 64) {
        float xv = xr[i];
        xbr[i] = __float2bfloat16(xv);
#pragma unroll
        for (int e = 0; e < NE; ++e) s[e] += xv * gw[e * H_DIM + i];
    }
#pragma unroll
    for (int e = 0; e < NE; ++e) {
        for (int off = 32; off > 0; off >>= 1) s[e] += __shfl_xor(s[e], off);
    }
    if (lane == 0) {
        float scores[NE], sfc[NE];
#pragma unroll
        for (int e = 0; e < NE; ++e) {
            scores[e] = 1.f / (1.f + __expf(-s[e]));
            sfc[e] = scores[e] + gb[e];
        }
        float gsc[4];
#pragma unroll
        for (int g = 0; g < 4; ++g) {
            float m1 = -1e30f, m2 = -1e30f;
#pragma unroll
            for (int j = 0; j < 4; ++j) {
                float v = sfc[4 * g + j];
                if (v > m1) { m2 = m1; m1 = v; } else if (v > m2) { m2 = v; }
            }
            gsc[g] = m1 + m2;
        }
        int g1 = 0;
        for (int g = 1; g < 4; ++g) if (gsc[g] > gsc[g1]) g1 = g;
        int g2 = -1;
        for (int g = 0; g < 4; ++g) {
            if (g == g1) continue;
            if (g2 < 0 || gsc[g] > gsc[g2]) g2 = g;
        }
        float tmp[NE];
#pragma unroll
        for (int e = 0; e < NE; ++e) {
            int gg = e >> 2;
            tmp[e] = (gg == g1 || gg == g2) ? sfc[e] : 0.0f;
        }
        int idxs[4]; float wk[4]; float wsum = 0.f;
#pragma unroll
        for (int k = 0; k < 4; ++k) {
            int bi = 0;
            for (int e = 1; e < NE; ++e) if (tmp[e] > tmp[bi]) bi = e;
            idxs[k] = bi; wk[k] = scores[bi]; wsum += scores[bi];
            tmp[bi] = -1e30f;
        }
        float inv = 1.f / (wsum + 1e-20f);
        for (int k = 0; k < 4; ++k) {
            int e = idxs[k];
            int pos = atomicAdd(&counts[e], 1);
            etok[e * T_TOK + pos] = t;
            ew[e * T_TOK + pos] = wk[k] * inv;   // SCALE = 1.0
        }
    }
}

// ------------------------------------------------------------- gate/up ------
// Grid (22, ne, 4). Block = [BM=256 tok x 64 I-cols]; wave w owns 64 tokens.
// 4-deep LDS ring, ONE raw barrier per K-step (lgkmcnt(0) + s_barrier +
// sched_barrier(0)). Staging loads for k+2 issued at step k stay in flight
// ACROSS barriers (compiler emits counted vmcnt for the cvt dependence) —
// unlike __syncthreads, which drains vmcnt(0) every step.
// [best-measured config: R4 = 487.96 us total, gateup ~134.5 us]
__global__ __launch_bounds__(256, 2) void gateup_kernel(
    const __hip_bfloat16* __restrict__ x_bf,
    const float* __restrict__ gproj, const float* __restrict__ uproj,
    const float* __restrict__ sgw, const float* __restrict__ suw,
    const int* __restrict__ counts, const int* __restrict__ etok,
    __hip_bfloat16* __restrict__ act, int e0)
{
    const int slot = blockIdx.y;
    const int e = e0 + slot;
    const int cnt = (e < NE) ? counts[e] : T_TOK;
    const int row0 = blockIdx.z * BM;
    if (row0 >= cnt) return;

    __shared__ int toks[BM];
    __shared__ __align__(16) __hip_bfloat16 Bg[4][64 * LDB];
    __shared__ __align__(16) __hip_bfloat16 Bu[4][64 * LDB];

    const int tid = threadIdx.x;
    {
        int r = row0 + tid;
        toks[tid] = (e < NE) ? ((r < cnt) ? etok[e * T_TOK + r] : 0) : r;
    }

    const int nb0 = blockIdx.x * 64;
    const float *wg, *wu;
    if (e < NE) {
        wg = gproj + (size_t)e * I_DIM * H_DIM;
        wu = uproj + (size_t)e * I_DIM * H_DIM;
    } else {
        wg = sgw + (size_t)(e - NE) * I_DIM * H_DIM;
        wu = suw + (size_t)(e - NE) * I_DIM * H_DIM;
    }
    // staging: thread -> (scol = tid>>2, sq = tid&3), 8 f32 each matrix
    const int scol = tid >> 2, sq = tid & 3;
    const float* sgp = wg + (size_t)(nb0 + scol) * H_DIM + sq * 8;
    const float* sup = wu + (size_t)(nb0 + scol) * H_DIM + sq * 8;
    const int lws = scol * LDB + sq * 8;   // lds write offset (bf16 elems)

    const int lane = tid & 63;
    const int w = tid >> 6;
    const int col = lane & 15, kq = lane >> 4;

    __syncthreads();   // toks visible (before any staging loads are issued)

    const __hip_bfloat16* ar[4];
#pragma unroll
    for (int mi = 0; mi < 4; ++mi)
        ar[mi] = x_bf + (size_t)toks[w * 64 + mi * 16 + col] * H_DIM + kq * 8;

    f32x4 accg[4][4], accu[4][4];
#pragma unroll
    for (int mi = 0; mi < 4; ++mi)
#pragma unroll
        for (int ni = 0; ni < 4; ++ni) {
            accg[mi][ni] = (f32x4){0.f, 0.f, 0.f, 0.f};
            accu[mi][ni] = (f32x4){0.f, 0.f, 0.f, 0.f};
        }

    // prologue: data for k=0 and k=1; write k=0 into ring buf 0
    float4 S0[4], S1[4];
    S0[0] = ((const float4*)sgp)[0]; S0[1] = ((const float4*)sgp)[1];
    S0[2] = ((const float4*)sup)[0]; S0[3] = ((const float4*)sup)[1];
    {
        const float* pg = sgp + 32; const float* pu = sup + 32;
        S1[0] = ((const float4*)pg)[0]; S1[1] = ((const float4*)pg)[1];
        S1[2] = ((const float4*)pu)[0]; S1[3] = ((const float4*)pu)[1];
    }
    *(bf16x8*)&Bg[0][lws] = cvt8(S0[0], S0[1]);
    *(bf16x8*)&Bu[0][lws] = cvt8(S0[2], S0[3]);

    // one step: W-phase (A loads, stage k+2, write k+1) | barrier | R-phase
    auto gu_step = [&](int k, float4 (&wrS)[4], float4 (&ldS)[4],
                       bool doStage, bool doWrite) {
        bf16x8 a[4];
#pragma unroll
        for (int mi = 0; mi < 4; ++mi) a[mi] = *(const bf16x8*)(ar[mi] + k * 32);
        if (doStage) {
            const float* pg = sgp + (k + 2) * 32;
            const float* pu = sup + (k + 2) * 32;
            ldS[0] = ((const float4*)pg)[0]; ldS[1] = ((const float4*)pg)[1];
            ldS[2] = ((const float4*)pu)[0]; ldS[3] = ((const float4*)pu)[1];
        }
        if (doWrite) {
            const int bw = (k + 1) & 3;
            *(bf16x8*)&Bg[bw][lws] = cvt8(wrS[0], wrS[1]);
            *(bf16x8*)&Bu[bw][lws] = cvt8(wrS[2], wrS[3]);
        }
        asm volatile("s_waitcnt lgkmcnt(0)" ::: "memory");  // writes visible
        __builtin_amdgcn_s_barrier();                        // no vmcnt drain
        __builtin_amdgcn_sched_barrier(0);                   // no hoist past bar
        const int br = k & 3;
        bf16x8 bg[4], bu[4];
#pragma unroll
        for (int ni = 0; ni < 4; ++ni) {
            bg[ni] = *(const bf16x8*)&Bg[br][(ni * 16 + col) * LDB + kq * 8];
            bu[ni] = *(const bf16x8*)&Bu[br][(ni * 16 + col) * LDB + kq * 8];
        }
#pragma unroll
        for (int mi = 0; mi < 4; ++mi)
#pragma unroll
            for (int ni = 0; ni < 4; ++ni) {
                accg[mi][ni] = __builtin_amdgcn_mfma_f32_16x16x32_bf16(a[mi], bg[ni], accg[mi][ni], 0, 0, 0);
                accu[mi][ni] = __builtin_amdgcn_mfma_f32_16x16x32_bf16(a[mi], bu[ni], accu[mi][ni], 0, 0, 0);
            }
    };

    for (int k = 0; k < 32; k += 2) {
        gu_step(k,     S1, S0, k + 2 < 32, true);        // write k+1, stage k+2
        gu_step(k + 1, S0, S1, k + 3 < 32, k + 2 < 32);  // write k+2, stage k+3
    }

    // epilogue: silu(g)*u -> act (zeros for padded rows so down reads zeros)
#pragma unroll
    for (int mi = 0; mi < 4; ++mi)
#pragma unroll
        for (int ni = 0; ni < 4; ++ni)
#pragma unroll
            for (int r = 0; r < 4; ++r) {
                int lrow = w * 64 + mi * 16 + kq * 4 + r;
                int grow = row0 + lrow;
                float g = accg[mi][ni][r];
                float a = (grow < cnt) ? (g / (1.f + __expf(-g)) * accu[mi][ni][r]) : 0.f;
                act[((size_t)slot * T_TOK + grow) * I_DIM + nb0 + ni * 16 + col] =
                    __float2bfloat16(a);
            }
}

// ---------------------------------------------------------------- down ------
// 1-D grid, XCD-clustered: all 16 nb-blocks of one (slot,z) group share the
// same 704KB act slice; mapping hw%8 == group%8 puts them on one XCD's L2.
// Same 4-deep ring / single-raw-barrier K-loop; K = I_DIM/32 = 44 steps.
__global__ __launch_bounds__(256, 3) void down_kernel(
    const __hip_bfloat16* __restrict__ act,
    const float* __restrict__ dproj, const float* __restrict__ sdw,
    const int* __restrict__ counts, const int* __restrict__ etok,
    const float* __restrict__ ew, float* __restrict__ y, int e0, int ne)
{
    const int hw = blockIdx.x;
    const int c = hw & 7, t = hw >> 3;
    const int nbt = t & 15, gh = t >> 4;
    const int g = c + 8 * gh;
    if (g >= ne * 4) return;           // Gp padding
    const int slot = g % ne;
    const int z = g / ne;

    const int e = e0 + slot;
    const int cnt = (e < NE) ? counts[e] : T_TOK;
    const int row0 = z * BM;
    if (row0 >= cnt) return;

    __shared__ int toks[BM];
    __shared__ float wts[BM];
    __shared__ __align__(16) __hip_bfloat16 Bd[4][64 * LDB];

    const int tid = threadIdx.x;
    {
        int r = row0 + tid;
        if (e < NE) {
            bool ok = r < cnt;
            toks[tid] = ok ? etok[e * T_TOK + r] : 0;
            wts[tid]  = ok ? ew[e * T_TOK + r] : 0.f;
        } else { toks[tid] = r; wts[tid] = 1.f; }
    }

    const int nb0 = nbt * 64;
    const float* wd;
    int wstride;
    if (e < NE) { wd = dproj + (size_t)e * H_DIM * I_DIM; wstride = I_DIM; }
    else        { wd = sdw + (size_t)(e - NE) * I_DIM;    wstride = 2 * I_DIM; }
    const int scol = tid >> 2, sq = tid & 3;
    const float* sdp = wd + (size_t)(nb0 + scol) * wstride + sq * 8;
    const int lws = scol * LDB + sq * 8;

    const int lane = tid & 63;
    const int w = tid >> 6;
    const int col = lane & 15, kq = lane >> 4;

    __syncthreads();   // toks/wts visible

    const __hip_bfloat16* ar[4];
#pragma unroll
    for (int mi = 0; mi < 4; ++mi)
        ar[mi] = act + ((size_t)slot * T_TOK + row0 + w * 64 + mi * 16 + col) * I_DIM + kq * 8;

    f32x4 acc[4][4];
#pragma unroll
    for (int mi = 0; mi < 4; ++mi)
#pragma unroll
        for (int ni = 0; ni < 4; ++ni) acc[mi][ni] = (f32x4){0.f, 0.f, 0.f, 0.f};

    float4 S0[2], S1[2];
    S0[0] = ((const float4*)sdp)[0]; S0[1] = ((const float4*)sdp)[1];
    {
        const float* pd = sdp + 32;
        S1[0] = ((const float4*)pd)[0]; S1[1] = ((const float4*)pd)[1];
    }
    *(bf16x8*)&Bd[0][lws] = cvt8(S0[0], S0[1]);

    auto d_step = [&](int k, float4 (&wrS)[2], float4 (&ldS)[2],
                      bool doStage, bool doWrite) {
        bf16x8 a[4];
#pragma unroll
        for (int mi = 0; mi < 4; ++mi) a[mi] = *(const bf16x8*)(ar[mi] + k * 32);
        if (doStage) {
            const float* pd = sdp + (k + 2) * 32;
            ldS[0] = ((const float4*)pd)[0]; ldS[1] = ((const float4*)pd)[1];
        }
        if (doWrite) {
            const int bw = (k + 1) & 3;
            *(bf16x8*)&Bd[bw][lws] = cvt8(wrS[0], wrS[1]);
        }
        asm volatile("s_waitcnt lgkmcnt(0)" ::: "memory");
        __builtin_amdgcn_s_barrier();
        __builtin_amdgcn_sched_barrier(0);
        const int br = k & 3;
        bf16x8 b[4];
#pragma unroll
        for (int ni = 0; ni < 4; ++ni)
            b[ni] = *(const bf16x8*)&Bd[br][(ni * 16 + col) * LDB + kq * 8];
#pragma unroll
        for (int mi = 0; mi < 4; ++mi)
#pragma unroll
            for (int ni = 0; ni < 4; ++ni)
                acc[mi][ni] = __builtin_amdgcn_mfma_f32_16x16x32_bf16(a[mi], b[ni], acc[mi][ni], 0, 0, 0);
    };

    const int KS = I_DIM / 32;   // 44
    for (int k = 0; k < KS; k += 2) {
        d_step(k,     S1, S0, k + 2 < KS, true);
        d_step(k + 1, S0, S1, k + 3 < KS, k + 2 < KS);
    }

#pragma unroll
    for (int mi = 0; mi < 4; ++mi)
#pragma unroll
        for (int ni = 0; ni < 4; ++ni)
#pragma unroll
            for (int r = 0; r < 4; ++r) {
                int lrow = w * 64 + mi * 16 + kq * 4 + r;
                int grow = row0 + lrow;
                if (grow < cnt)
                    atomicAdd(&y[(size_t)toks[lrow] * H_DIM + nb0 + ni * 16 + col],
                              acc[mi][ni][r] * wts[lrow]);
            }
}

// -------------------------------------------------------------- launch ------
extern "C" void kernel_launch(void* const* d_in, const int* in_sizes, int n_in,
                              void* d_out, int out_size, void* d_ws, size_t ws_size,
                              hipStream_t stream) {
    (void)in_sizes; (void)n_in; (void)out_size;
    const float* x  = (const float*)d_in[0];
    const float* gw = (const float*)d_in[1];
    const float* gb = (const float*)d_in[2];
    const float* gp = (const float*)d_in[3];
    const float* up = (const float*)d_in[4];
    const float* dp = (const float*)d_in[5];
    const float* sg = (const float*)d_in[6];
    const float* su = (const float*)d_in[7];
    const float* sd = (const float*)d_in[8];
    float* out = (float*)d_out;

    char* ws = (char*)d_ws;
    int*   counts = (int*)ws;                                    // @0      (64 B)
    int*   etok   = (int*)(ws + 256);                            // 64 KB
    float* ew     = (float*)(ws + 256 + 65536);                  // 64 KB
    __hip_bfloat16* x_bf = (__hip_bfloat16*)(ws + 131328);       // 2 MB
    __hip_bfloat16* act  = (__hip_bfloat16*)(ws + 2228480);      // up to ~52 MB

    size_t fixed = 2228480;
    size_t per_e = (size_t)T_TOK * I_DIM * 2;                    // 2.75 MB / slot
    int cap = NEP;
    if (ws_size < fixed + (size_t)NEP * per_e) {
        cap = (ws_size > fixed + per_e) ? (int)((ws_size - fixed) / per_e) : 1;
        if (cap < 1) cap = 1;
    }

    hipMemsetAsync(ws, 0, 256, stream);                          // counts
    hipMemsetAsync(out, 0, (size_t)T_TOK * H_DIM * 4, stream);   // d_out is poisoned

    gate_kernel<<<dim3(T_TOK), dim3(64), 0, stream>>>(x, gw, gb, counts, etok, ew, x_bf);

    for (int e0 = 0; e0 < NEP; e0 += cap) {
        int ne = NEP - e0 < cap ? NEP - e0 : cap;
        gateup_kernel<<<dim3(I_DIM / 64, ne, T_TOK / BM), dim3(256), 0, stream>>>(
            x_bf, gp, up, sg, su, counts, etok, act, e0);
        int Gp = ((ne * 4 + 7) / 8) * 8;                         // XCD-bijective pad
        down_kernel<<<dim3(16 * Gp), dim3(256), 0, stream>>>(
            act, dp, sd, counts, etok, ew, out, e0, ne);
    }
}